// Round 19
// baseline (3965.791 us; speedup 1.0000x reference)
//
#include <hip/hip_runtime.h>
#include <math.h>

#define B    32
#define H    1024
#define EMB  512
#define V    32000
#define SOS  1

// ws float offsets (R15 layout + Pkey). x/h state: [k][b], b contiguous.
#define OFF_HA  16384        // H*B
#define OFF_HB  49152        // H*B
#define OFF_P   81920        // float4[500][32] = 64000 floats
#define OFF_C   145920       // T*B
#define OFF_HHI 147968       // short[H*B]
#define OFF_HLO 164352
#define OFF_WHI 180736       // short[V*H]
#define OFF_WLO 16564736
#define OFF_PK  32948736     // u64[500][32] = 32000 floats

#define NEG_INF (-3.0e38f)

typedef float f4v   __attribute__((ext_vector_type(4)));
typedef short short8v __attribute__((ext_vector_type(8)));
typedef float f32x4 __attribute__((ext_vector_type(4)));
typedef unsigned long long u64;

#define MF(a,b,c) c = __builtin_amdgcn_mfma_f32_16x16x32_bf16(a, b, c, 0, 0, 0)

__device__ __forceinline__ unsigned short rnb(float x) {
    unsigned u = __float_as_uint(x);
    unsigned r = u + 0x7FFFu + ((u >> 16) & 1u);
    return (unsigned short)(r >> 16);
}
__device__ __forceinline__ float bfh(unsigned short s) {
    return __uint_as_float(((unsigned)s) << 16);
}
__device__ __forceinline__ void sm_merge(float& m, float& l, int& a,
                                         float om, float ol, int oa)
{
    const bool take = (om > m) || (om == m && oa < a);
    const float mn = take ? om : m;
    const int   an = take ? oa : a;
    l = l * expf(m - mn) + ol * expf(om - mn);
    m = mn; a = an;
}
__device__ __forceinline__ void sm2(float& m, float& l, float om, float ol)
{
    const float mn = fmaxf(m, om);
    l = l * expf(m - mn) + ol * expf(om - mn);
    m = mn;
}

// ---------------------------------------------------------------- INIT (+ W hi/lo split)
__global__ void k_init(const float* __restrict__ ih, const float* __restrict__ wout,
                       float* __restrict__ ws)
{
    const size_t idx = (size_t)blockIdx.x * blockDim.x + threadIdx.x;
    const size_t stride = (size_t)gridDim.x * blockDim.x;
    short* Hhi = (short*)(ws + OFF_HHI);
    short* Hlo = (short*)(ws + OFF_HLO);
    for (size_t i = idx; i < H * B; i += stride) {
        int j = (int)(i >> 5), b = (int)(i & 31);
        const float hv = ih[(size_t)b * H + j];
        ws[OFF_HA + j * 32 + b] = hv;
        const unsigned short hi = rnb(hv);
        const int pidx = ((j >> 3) * 32 + b) * 8 + (j & 7);
        Hhi[pidx] = (short)hi;
        Hlo[pidx] = (short)rnb(hv - bfh(hi));
    }
    short* Whi = (short*)(ws + OFF_WHI);
    short* Wlo = (short*)(ws + OFF_WLO);
    for (size_t i = idx; i < (size_t)V * H; i += stride) {
        const float x = wout[i];
        const unsigned short hi = rnb(x);
        Whi[i] = (short)hi;
        Wlo[i] = (short)rnb(x - bfh(hi));
    }
}

// ---------------------------------------------------------------- GRU + fused FIN2(prev step)
// 256 blocks x 1024 thr, ~94.6 KB dyn LDS (1 blk/CU, 16 waves).
// Phase 0: all blocks u64-argmax TOK from Pkey (int compares only); block 0 also C_prev.
// Phase 1: x = tanh(emb[TOK]) -> LDS [512][33]. Phase 2: R15 gru body.
#define XLF   16896                       // 512*33
#define DSMA  ((XLF + 4608 + 2112 + 32) * 4)   // xl | sred | kred(u64) | tok = 94592 B

__global__ __launch_bounds__(1024) void k_gruf(
    const float4* __restrict__ P, const u64* __restrict__ Pkey,
    const float* __restrict__ emb, const float* __restrict__ hold,
    const float* __restrict__ wih, const float* __restrict__ bih,
    const float* __restrict__ whh, const float* __restrict__ bhh,
    float* __restrict__ hnew, short* __restrict__ Hhi, short* __restrict__ Hlo,
    float* __restrict__ C_prev, int first)
{
    extern __shared__ __align__(16) float dsm[];
    float* xl   = dsm;                    // [512][33]
    float* sred = dsm + XLF;              // [4][1152] (gru reduce; cm/cl alias in phase 0)
    u64*   kred = (u64*)(dsm + XLF + 4608);  // [32][33]
    int*   tokl = (int*)(dsm + XLF + 4608 + 2112);

    const int t   = threadIdx.x;
    const int blk = blockIdx.x;

    // ---------- Phase 0: TOK (+C for block 0)
    {
        const int b = t & 31, seg = t >> 5;
        float* cm = sred;                 // [32][33]
        float* cl = sred + 1056;
        u64 kk = 0; float m = NEG_INF, lsum = 0.f;
        if (!first) {
            for (int e = seg; e < 500; e += 32) {
                const u64 ke = Pkey[e * 32 + b];
                if (ke > kk) kk = ke;
                if (blk == 0) {
                    const float4 p = P[e * 32 + b];
                    sm2(m, lsum, p.x, p.y);
                }
            }
        }
        kred[seg * 33 + b] = kk;
        if (blk == 0) { cm[seg * 33 + b] = m; cl[seg * 33 + b] = lsum; }
        __syncthreads();
        for (int s = 16; s > 0; s >>= 1) {
            if (t < s * 32) {
                const u64 o = kred[(seg + s) * 33 + b];
                if (o > kred[seg * 33 + b]) kred[seg * 33 + b] = o;
                if (blk == 0) {
                    float mm = cm[seg * 33 + b], ll = cl[seg * 33 + b];
                    sm2(mm, ll, cm[(seg + s) * 33 + b], cl[(seg + s) * 33 + b]);
                    cm[seg * 33 + b] = mm; cl[seg * 33 + b] = ll;
                }
            }
            __syncthreads();
        }
        if (t < 32) {
            tokl[t] = first ? SOS : (int)(~(unsigned)(kred[t] & 0xFFFFFFFFull));
            if (blk == 0 && !first) C_prev[t] = cm[t] + logf(cl[t]);
        }
        __syncthreads();
    }

    // ---------- Phase 1: stage x = tanh(emb[TOK]) into xl [k][b]
    {
        const int b = t & 31;
        const int TOK = tokl[b];
        const int kq0 = t >> 5;           // 0..31
#pragma unroll
        for (int it = 0; it < 4; ++it) {
            const int kq = kq0 + 32 * it; // 0..127
            const float4 e4 = *(const float4*)&emb[(size_t)TOK * EMB + kq * 4];
            xl[(4 * kq + 0) * 33 + b] = tanhf(e4.x);
            xl[(4 * kq + 1) * 33 + b] = tanhf(e4.y);
            xl[(4 * kq + 2) * 33 + b] = tanhf(e4.z);
            xl[(4 * kq + 3) * 33 + b] = tanhf(e4.w);
        }
    }
    __syncthreads();

    // ---------- Phase 2: R15 gru body (x from LDS)
    const int ks = t >> 7;
    const int pl = t & 127;
    const int p  = blk * 128 + pl;
    const int b  = p & 31;
    const int j  = p >> 5;

    float ar = 0.f, az = 0.f, ain = 0.f, ahn = 0.f;
    const int k0 = ks * 192, k1 = k0 + 192;

    const int xe = (k1 < EMB) ? k1 : EMB;
    for (int k = k0; k < xe; k += 4) {
        const float u0 = xl[(k + 0) * 33 + b];
        const float u1 = xl[(k + 1) * 33 + b];
        const float u2 = xl[(k + 2) * 33 + b];
        const float u3 = xl[(k + 3) * 33 + b];
        const float4 w0 = *(const float4*)&wih[(size_t)(0 * H + j) * EMB + k];
        const float4 w1 = *(const float4*)&wih[(size_t)(1 * H + j) * EMB + k];
        const float4 w2 = *(const float4*)&wih[(size_t)(2 * H + j) * EMB + k];
        ar  = fmaf(w0.x, u0, fmaf(w0.y, u1, fmaf(w0.z, u2, fmaf(w0.w, u3, ar))));
        az  = fmaf(w1.x, u0, fmaf(w1.y, u1, fmaf(w1.z, u2, fmaf(w1.w, u3, az))));
        ain = fmaf(w2.x, u0, fmaf(w2.y, u1, fmaf(w2.z, u2, fmaf(w2.w, u3, ain))));
    }
    const int hs = (k0 > EMB) ? k0 : EMB;
    for (int k = hs; k < k1; k += 4) {
        const int kh = k - EMB;
        const float u0 = hold[(kh + 0) * 32 + b];
        const float u1 = hold[(kh + 1) * 32 + b];
        const float u2 = hold[(kh + 2) * 32 + b];
        const float u3 = hold[(kh + 3) * 32 + b];
        const float4 w0 = *(const float4*)&whh[(size_t)(0 * H + j) * H + kh];
        const float4 w1 = *(const float4*)&whh[(size_t)(1 * H + j) * H + kh];
        const float4 w2 = *(const float4*)&whh[(size_t)(2 * H + j) * H + kh];
        ar  = fmaf(w0.x, u0, fmaf(w0.y, u1, fmaf(w0.z, u2, fmaf(w0.w, u3, ar))));
        az  = fmaf(w1.x, u0, fmaf(w1.y, u1, fmaf(w1.z, u2, fmaf(w1.w, u3, az))));
        ahn = fmaf(w2.x, u0, fmaf(w2.y, u1, fmaf(w2.z, u2, fmaf(w2.w, u3, ahn))));
    }

    sred[0 * 1152 + pl * 9 + ks] = ar;
    sred[1 * 1152 + pl * 9 + ks] = az;
    sred[2 * 1152 + pl * 9 + ks] = ain;
    sred[3 * 1152 + pl * 9 + ks] = ahn;
    __syncthreads();

    if (t < 128) {
        const int pp = blk * 128 + t;
        const int bb = pp & 31, jj = pp >> 5;
        float s0 = 0.f, s1 = 0.f, s2 = 0.f, s3 = 0.f;
#pragma unroll
        for (int q = 0; q < 8; ++q) {
            s0 += sred[0 * 1152 + t * 9 + q];
            s1 += sred[1 * 1152 + t * 9 + q];
            s2 += sred[2 * 1152 + t * 9 + q];
            s3 += sred[3 * 1152 + t * 9 + q];
        }
        float gr  = s0 + bih[jj]         + bhh[jj];
        float gz  = s1 + bih[H + jj]     + bhh[H + jj];
        float gin = s2 + bih[2 * H + jj];
        float ghn = s3 + bhh[2 * H + jj];
        float r = 1.f / (1.f + expf(-gr));
        float z = 1.f / (1.f + expf(-gz));
        float n = tanhf(gin + r * ghn);   // r multiplies hh-part only
        const int hidx = jj * 32 + bb;
        const float hv = (1.f - z) * n + z * hold[hidx];
        hnew[hidx] = hv;
        const unsigned short hi = rnb(hv);
        const unsigned short lo = rnb(hv - bfh(hi));
        const int pidx = ((jj >> 3) * 32 + bb) * 8 + (jj & 7);
        Hhi[pidx] = (short)hi;
        Hlo[pidx] = (short)lo;
    }
}

// ---------------------------------------------------------------- PROJ (R15 body + Pkey write)
__global__ __launch_bounds__(512, 4) void k_proj(
    const short* __restrict__ Whi, const short* __restrict__ Wlo,
    const short* __restrict__ Hhi, const short* __restrict__ Hlo,
    const float* __restrict__ bout, float* __restrict__ orow,
    float4* __restrict__ P, u64* __restrict__ Pkey)
{
    __shared__ float Red[4 * 32 * 33];
    __shared__ float Dt[32 * 68];
    __shared__ float bl[64];
    __shared__ float pm[2][32], pls[2][32];
    __shared__ int   pa[2][32];

    const int t   = threadIdx.x;
    const int blk = blockIdx.x;
    const int r0  = blk * 64;
    const int w   = t >> 6;
    const int mh  = w >> 2;
    const int kq  = w & 3;
    const int l   = t & 63;
    const int lr  = l & 15;
    const int lg  = l >> 4;

    if (t < 64) bl[t] = bout[r0 + t];

    const short* pAh = Whi + (size_t)(r0 + mh * 32 + lr) * H + lg * 8;
    const short* pAl = Wlo + (size_t)(r0 + mh * 32 + lr) * H + lg * 8;
    const short* pBh = Hhi + ((size_t)lg * 32 + lr) * 8;
    const short* pBl = Hlo + ((size_t)lg * 32 + lr) * 8;

    f32x4 acc00 = {0.f, 0.f, 0.f, 0.f};
    f32x4 acc01 = {0.f, 0.f, 0.f, 0.f};
    f32x4 acc10 = {0.f, 0.f, 0.f, 0.f};
    f32x4 acc11 = {0.f, 0.f, 0.f, 0.f};

#pragma unroll 2
    for (int i = 0; i < 8; ++i) {
        const int c = 4 * i + kq;
        const short8v a0h = *(const short8v*)(pAh + c * 32);
        const short8v a0l = *(const short8v*)(pAl + c * 32);
        const short8v a1h = *(const short8v*)(pAh + 16 * H + c * 32);
        const short8v a1l = *(const short8v*)(pAl + 16 * H + c * 32);
        const short8v b0h = *(const short8v*)(pBh + c * 1024);
        const short8v b0l = *(const short8v*)(pBl + c * 1024);
        const short8v b1h = *(const short8v*)(pBh + c * 1024 + 128);
        const short8v b1l = *(const short8v*)(pBl + c * 1024 + 128);
        MF(a0h, b0h, acc00); MF(a0h, b0l, acc00); MF(a0l, b0h, acc00);
        MF(a0h, b1h, acc01); MF(a0h, b1l, acc01); MF(a0l, b1h, acc01);
        MF(a1h, b0h, acc10); MF(a1h, b0l, acc10); MF(a1l, b0h, acc10);
        MF(a1h, b1h, acc11); MF(a1h, b1l, acc11); MF(a1l, b1h, acc11);
    }

    if (kq >= 2) {
        float* rp = Red + (mh * 2 + (kq - 2)) * 1056;
#pragma unroll
        for (int mt = 0; mt < 2; ++mt)
#pragma unroll
            for (int r = 0; r < 4; ++r) {
                const int row = mt * 16 + lg * 4 + r;
                rp[row * 33 + lr]      = mt ? acc10[r] : acc00[r];
                rp[row * 33 + 16 + lr] = mt ? acc11[r] : acc01[r];
            }
    }
    __syncthreads();
    if (kq < 2) {
        const float* rp = Red + (mh * 2 + kq) * 1056;
#pragma unroll
        for (int mt = 0; mt < 2; ++mt)
#pragma unroll
            for (int r = 0; r < 4; ++r) {
                const int row = mt * 16 + lg * 4 + r;
                const float e0 = rp[row * 33 + lr];
                const float e1 = rp[row * 33 + 16 + lr];
                if (mt) { acc10[r] += e0; acc11[r] += e1; }
                else    { acc00[r] += e0; acc01[r] += e1; }
            }
    }
    __syncthreads();
    if (kq == 1) {
        float* rp = Red + mh * 2 * 1056;
#pragma unroll
        for (int mt = 0; mt < 2; ++mt)
#pragma unroll
            for (int r = 0; r < 4; ++r) {
                const int row = mt * 16 + lg * 4 + r;
                rp[row * 33 + lr]      = mt ? acc10[r] : acc00[r];
                rp[row * 33 + 16 + lr] = mt ? acc11[r] : acc01[r];
            }
    }
    __syncthreads();

    if (kq == 0) {
        const float* rp = Red + mh * 2 * 1056;
        float val[2][2][4];
#pragma unroll
        for (int mt = 0; mt < 2; ++mt)
#pragma unroll
            for (int r = 0; r < 4; ++r) {
                const int row = mt * 16 + lg * 4 + r;
                const float bo = bl[mh * 32 + row];
                val[mt][0][r] = (mt ? acc10[r] : acc00[r]) + rp[row * 33 + lr] + bo;
                val[mt][1][r] = (mt ? acc11[r] : acc01[r]) + rp[row * 33 + 16 + lr] + bo;
            }
#pragma unroll
        for (int mt = 0; mt < 2; ++mt)
#pragma unroll
            for (int nt = 0; nt < 2; ++nt)
#pragma unroll
                for (int r = 0; r < 4; ++r)
                    Dt[(nt * 16 + lr) * 68 + mh * 32 + mt * 16 + lg * 4 + r] = val[mt][nt][r];

#pragma unroll
        for (int nt = 0; nt < 2; ++nt) {
            float m = val[0][nt][0], ls = 1.f;
            int a = r0 + mh * 32 + lg * 4;
#pragma unroll
            for (int q = 1; q < 8; ++q) {
                const int mt = q >> 2, r = q & 3;
                const float x = val[mt][nt][r];
                const int row = r0 + mh * 32 + mt * 16 + lg * 4 + r;
                if (x > m) { ls = ls * expf(m - x) + 1.f; m = x; a = row; }
                else       { ls += expf(x - m); }
            }
            sm_merge(m, ls, a, __shfl_xor(m, 16), __shfl_xor(ls, 16), __shfl_xor(a, 16));
            sm_merge(m, ls, a, __shfl_xor(m, 32), __shfl_xor(ls, 32), __shfl_xor(a, 32));
            if (lg == 0) { pm[mh][nt * 16 + lr] = m; pls[mh][nt * 16 + lr] = ls; pa[mh][nt * 16 + lr] = a; }
        }
    }
    __syncthreads();

    if (t < 32) {
        float m = pm[0][t], ls = pls[0][t]; int a = pa[0][t];
        sm_merge(m, ls, a, pm[1][t], pls[1][t], pa[1][t]);
        P[blk * 32 + t] = make_float4(m, ls, (float)a, 0.f);
        unsigned u = __float_as_uint(m);
        u = (u >> 31) ? ~u : (u | 0x80000000u);
        Pkey[blk * 32 + t] = ((u64)u << 32) | (unsigned)(~(unsigned)a);
    }

    const int sb = t >> 4, rq = t & 15;
    const f4v v = *(const f4v*)&Dt[sb * 68 + rq * 4];
    __builtin_nontemporal_store(v, (f4v*)&orow[(size_t)sb * V + r0 + rq * 4]);
}

// ---------------------------------------------------------------- FINLAST: C for last step
__global__ __launch_bounds__(1024) void k_finlast(
    const float4* __restrict__ P, float* __restrict__ C_last)
{
    __shared__ float fm[1056], fl[1056];
    const int t = threadIdx.x;
    const int seg = t >> 5, b = t & 31;
    float m = NEG_INF, l = 0.f;
    for (int e = seg; e < 500; e += 32) {
        const float4 p = P[e * 32 + b];
        sm2(m, l, p.x, p.y);
    }
    fm[seg * 33 + b] = m; fl[seg * 33 + b] = l;
    __syncthreads();
    for (int s = 16; s > 0; s >>= 1) {
        if (t < s * 32) {
            float mm = fm[seg * 33 + b], ll = fl[seg * 33 + b];
            sm2(mm, ll, fm[(seg + s) * 33 + b], fl[(seg + s) * 33 + b]);
            fm[seg * 33 + b] = mm; fl[seg * 33 + b] = ll;
        }
        __syncthreads();
    }
    if (t < 32) C_last[t] = fm[t] + logf(fl[t]);
}

// ---------------------------------------------------------------- deferred subtract
__global__ __launch_bounds__(256) void k_sub(float* __restrict__ out,
                                             const float* __restrict__ C)
{
    const int r = blockIdx.x;
    const float c = C[r];
    f4v* row = (f4v*)(out + (size_t)r * V);
    for (int v = threadIdx.x; v < V / 4; v += 256) {
        f4v x = __builtin_nontemporal_load(&row[v]);
        x -= c;
        __builtin_nontemporal_store(x, &row[v]);
    }
}

// ---------------------------------------------------------------- launch
extern "C" void kernel_launch(void* const* d_in, const int* in_sizes, int n_in,
                              void* d_out, int out_size, void* d_ws, size_t ws_size,
                              hipStream_t stream)
{
    const float* p_ih   = (const float*)d_in[0];
    // d_in[1] encoder_outputs unused; d_in[2] tgt_len recovered from out_size
    const float* p_emb  = (const float*)d_in[3];
    const float* p_wih  = (const float*)d_in[4];
    const float* p_bih  = (const float*)d_in[5];
    const float* p_whh  = (const float*)d_in[6];
    const float* p_bhh  = (const float*)d_in[7];
    const float* p_wout = (const float*)d_in[8];
    const float* p_bout = (const float*)d_in[9];
    float* out = (float*)d_out;
    float* ws  = (float*)d_ws;
    const int T = out_size / (B * V);

    float*  hA  = ws + OFF_HA;
    float*  hB  = ws + OFF_HB;
    float4* P   = (float4*)(ws + OFF_P);
    float*  C   = ws + OFF_C;
    short*  Hhi = (short*)(ws + OFF_HHI);
    short*  Hlo = (short*)(ws + OFF_HLO);
    short*  Whi = (short*)(ws + OFF_WHI);
    short*  Wlo = (short*)(ws + OFF_WLO);
    u64*    PK  = (u64*)(ws + OFF_PK);

    hipFuncSetAttribute((const void*)k_gruf,
                        hipFuncAttributeMaxDynamicSharedMemorySize, DSMA);

    k_init<<<2048, 256, 0, stream>>>(p_ih, p_wout, ws);

    for (int st = 0; st < T; ++st) {
        float* hold = (st & 1) ? hB : hA;
        float* hnew = (st & 1) ? hA : hB;
        float* orow = out + (size_t)st * B * V;
        float* Cprv = C + (st > 0 ? (st - 1) * B : 0);
        k_gruf<<<256, 1024, DSMA, stream>>>(P, PK, p_emb, hold,
                                            p_wih, p_bih, p_whh, p_bhh,
                                            hnew, Hhi, Hlo, Cprv, st == 0 ? 1 : 0);
        k_proj<<<500, 512, 0, stream>>>(Whi, Wlo, Hhi, Hlo, p_bout, orow, P, PK);
    }
    k_finlast<<<1, 1024, 0, stream>>>(P, C + (T - 1) * B);
    k_sub<<<T * B, 256, 0, stream>>>(out, C);
}